// Round 5
// baseline (496.034 us; speedup 1.0000x reference)
//
#include <hip/hip_runtime.h>
#include <hip/hip_bf16.h>

// Problem constants
#define NB   4
#define CIN  64
#define COUT 128
#define SDIM 512
#define DIM  48
#define SP   (DIM*DIM*DIM)   // 110592
#define TAPS 27
#define KTOT (CIN*TAPS)      // 1728

// ---- small-param layout (float offsets at base of ws) ----
#define WS_S1P 0                         // [NB*CIN]       1+scale
#define WS_SH  (WS_S1P + NB*CIN)         // [NB*CIN]       shift
#define WS_KM  (WS_SH + NB*CIN)          // [NB*CIN*TAPS]  kmod
// ---- fast path byte offsets ----
#define XPB_OFF   32768ull                        // padded mod x (bf16 channel-last), 64 MB
#define XPB_BYTES (4ull*125000ull*64ull*2ull)     // 64,000,000
#define WSBF_OFF  (XPB_OFF + XPB_BYTES)
#define WSBF_BYTES ((size_t)NB*27*8*128*8*2)      // 1,769,472

typedef __attribute__((ext_vector_type(4))) float  f32x4;
typedef __attribute__((ext_vector_type(8))) short  short8;
typedef __attribute__((ext_vector_type(8))) unsigned short u16x8;

__device__ __forceinline__ void gld16(const void* g, void* l) {
    __builtin_amdgcn_global_load_lds(
        (const __attribute__((address_space(1))) void*)g,
        (__attribute__((address_space(3))) void*)l, 16, 0, 0);
}

// ---------------------------------------------------------------------------
// Kernel A: style dot products. One wave per row.
// rows: [0,64)=scale, [64,128)=shift, [128,1856)=kmod, per sample b.
// ---------------------------------------------------------------------------
__global__ void modparams_kernel(const float* __restrict__ style,
                                 const float* __restrict__ w_scale, const float* __restrict__ b_scale,
                                 const float* __restrict__ w_shift, const float* __restrict__ b_shift,
                                 const float* __restrict__ w_kmod,  const float* __restrict__ b_kmod,
                                 float* __restrict__ ws) {
    const int ROWS = 2 * CIN + CIN * TAPS;  // 1856
    int gwave = (blockIdx.x * blockDim.x + threadIdx.x) >> 6;
    int lane  = threadIdx.x & 63;
    if (gwave >= NB * ROWS) return;
    int b = gwave / ROWS;
    int r = gwave % ROWS;

    const float* srow = style + b * SDIM;
    const float* mrow;
    float bias, add = 0.f;
    float* dst;
    if (r < CIN) {
        mrow = w_scale + r * SDIM; bias = b_scale[r];
        dst = ws + WS_S1P + b * CIN + r; add = 1.f;          // store (1+scale)
    } else if (r < 2 * CIN) {
        int c = r - CIN;
        mrow = w_shift + c * SDIM; bias = b_shift[c];
        dst = ws + WS_SH + b * CIN + c;
    } else {
        int t = r - 2 * CIN;
        mrow = w_kmod + t * SDIM; bias = b_kmod[t];
        dst = ws + WS_KM + b * (CIN * TAPS) + t;
    }

    float acc = 0.f;
    for (int k = lane; k < SDIM; k += 64) acc += srow[k] * mrow[k];
    #pragma unroll
    for (int off = 32; off; off >>= 1) acc += __shfl_down(acc, off);
    if (lane == 0) *dst = acc + bias + add;
}

// ---------------------------------------------------------------------------
// WSBF2[(((b*27+tau)*8 + s)*128 + o)*8 + j] = bf16(weight[o, c=s*8+j, tau] *
//                                                  (1 + kmod[b, c, tau]))
// Linear gld16 staging stream; conflict-free af reads.
// ---------------------------------------------------------------------------
__global__ void build_wsbf2_kernel(const float* __restrict__ weight, const float* __restrict__ ws,
                                   unsigned short* __restrict__ wsbf) {
    int d = blockIdx.x * blockDim.x + threadIdx.x;
    if (d >= NB * 27 * 8 * 128 * 8) return;
    int j   = d & 7;
    int o   = (d >> 3) & 127;
    int s   = (d >> 10) & 7;
    int rem = d >> 13;
    int tau = rem % 27;
    int b   = rem / 27;
    int c   = s * 8 + j;
    float wm = weight[(o * CIN + c) * TAPS + tau] * (1.f + ws[WS_KM + b * KTOT + c * TAPS + tau]);
    __hip_bfloat16 h = __float2bfloat16(wm);
    wsbf[d] = *(unsigned short*)&h;
}

// ---------------------------------------------------------------------------
// Pad + modulate + transpose to channel-last bf16: xpb[b][pz][py][px][c]
// ---------------------------------------------------------------------------
__global__ __launch_bounds__(256) void pad_kernel(const float* __restrict__ x,
                                                  const float* __restrict__ ws,
                                                  unsigned short* __restrict__ xpb) {
    __shared__ unsigned short lxm[48 * 72];   // [w][c], row stride 144B (16B-aligned)
    int bid = blockIdx.x;
    int py = bid % 50;
    int pz = (bid / 50) % 50;
    int b  = bid / 2500;
    int t = threadIdx.x;
    bool interior = (pz >= 1 && pz <= 48 && py >= 1 && py <= 48);
    if (interior) {
        int z = pz - 1, y = py - 1;
        const float* xr = x + (size_t)b * CIN * SP + (size_t)z * (DIM*DIM) + y * DIM;
        for (int i = t; i < 3072; i += 256) {
            int c = i / 48, w = i % 48;
            float v = xr[(size_t)c * SP + w];
            float m = v * ws[WS_S1P + b * CIN + c] + ws[WS_SH + b * CIN + c];
            __hip_bfloat16 h = __float2bfloat16(m);
            lxm[w * 72 + c] = *(unsigned short*)&h;
        }
    }
    __syncthreads();
    unsigned short* dst = xpb + (size_t)b * 8000000ull + ((size_t)pz * 2500 + py * 50) * 64;
    for (int i8 = t; i8 < 400; i8 += 256) {
        int w  = i8 >> 3;          // padded px
        int c8 = (i8 & 7) * 8;
        u16x8 v = {};
        if (interior && w >= 1 && w <= 48)
            v = *(const u16x8*)&lxm[(w - 1) * 72 + c8];
        *(u16x8*)(dst + i8 * 8) = v;
    }
}

// ---------------------------------------------------------------------------
// Conv v3: block = 128 couts x 256 positions (4z x 8y x 8x box), 512 thr.
// Wave (mh, wz): M-half mh (64 couts), z-plane wz -> 64 positions. 4x4 frags.
// A (16 KB/tap) in LDS double-buffer (32 KB total -> 2 blocks/CU).
// B fragments loaded DIRECTLY from global (xpb, L2/L3-resident).
// ---------------------------------------------------------------------------
__global__ __launch_bounds__(512, 4) void conv_fast3_kernel(
    const unsigned short* __restrict__ xpb,
    const unsigned short* __restrict__ wsbf,
    const float* __restrict__ bias,
    float* __restrict__ out)
{
    __shared__ unsigned short At[2][8192];     // 2 x 16,384 B

    const int t    = threadIdx.x;
    const int lane = t & 63;
    const int wid  = t >> 6;        // 0..7
    const int wz   = wid & 3;       // z-plane
    const int mh   = wid >> 2;      // M half (0/1)

    // XCD-aware bijective swizzle: 1728 = 8 * 216
    int bid0 = blockIdx.x;
    int bid  = (bid0 & 7) * 216 + (bid0 >> 3);
    int tile = bid % 432;
    int b    = bid / 432;
    int tx = tile % 6;
    int ty = (tile / 6) % 6;
    int tz = tile / 36;             // 0..11
    int x0 = tx * 8, y0 = ty * 8, z0 = tz * 4;

    const unsigned short* xb = xpb + (size_t)b * 8000000ull;
    const unsigned short* wb = wsbf + (size_t)b * (27 * 8 * 128 * 8);

    // ---- stage A tap 0 (linear) ----
    gld16(wb + (size_t)t * 8,         &At[0][t * 8]);
    gld16(wb + (size_t)(512 + t) * 8, &At[0][(512 + t) * 8]);
    __syncthreads();

    const int col  = lane & 15;
    const int krow = lane >> 4;   // 0..3
    const int cy   = col >> 3;    // 0..1
    const int cx   = col & 7;     // 0..7

    // per-lane base into xpb (shorts)
    const unsigned short* xw = xb
        + ((size_t)(z0 + wz) * 2500 + (size_t)(y0 + cy) * 50 + (x0 + cx)) * 64
        + krow * 8;

    f32x4 acc[4][4] = {};
    int buf = 0;
    const int chfirst = wid & 1;   // stagger ch order across waves

    for (int tap = 0; tap < 27; ++tap) {
        // prefetch A for next tap (linear stream) into the other buffer
        if (tap < 26) {
            const unsigned short* wsrc = wb + (size_t)(tap + 1) * 8192;
            gld16(wsrc + t * 8,         &At[buf ^ 1][t * 8]);
            gld16(wsrc + (512 + t) * 8, &At[buf ^ 1][(512 + t) * 8]);
        }
        int kd = tap / 9;
        int r9 = tap - kd * 9;
        int kh = r9 / 3;
        int kw = r9 - kh * 3;
        int toff = (kd * 2500 + kh * 50 + kw) * 64;

        const unsigned short* Ab = At[buf];
        #pragma unroll
        for (int ci = 0; ci < 2; ++ci) {
            int ch = ci ^ chfirst;
            int slot = ch * 4 + krow;
            short8 af[4], bf[4];
            #pragma unroll
            for (int mf = 0; mf < 4; ++mf)
                af[mf] = *(const short8*)&Ab[(slot * 128 + mh * 64 + mf * 16 + col) * 8];
            #pragma unroll
            for (int nf = 0; nf < 4; ++nf)
                bf[nf] = *(const short8*)(xw + toff + ch * 32 + nf * 6400);
            __builtin_amdgcn_s_setprio(1);
            #pragma unroll
            for (int mf = 0; mf < 4; ++mf)
                #pragma unroll
                for (int nf = 0; nf < 4; ++nf)
                    acc[mf][nf] = __builtin_amdgcn_mfma_f32_16x16x32_bf16(af[mf], bf[nf], acc[mf][nf], 0, 0, 0);
            __builtin_amdgcn_s_setprio(0);
        }

        __syncthreads();   // A[tap+1] landed (vmcnt drain); reads of At[buf] done
        buf ^= 1;
    }

    // ---- epilogue: + bias, store ----
    int z = z0 + wz;
    #pragma unroll
    for (int mf = 0; mf < 4; ++mf) {
        f32x4 bv = *(const f32x4*)&bias[mh * 64 + mf * 16 + krow * 4];
        #pragma unroll
        for (int nf = 0; nf < 4; ++nf) {
            int y = y0 + nf * 2 + cy;
            int xx = x0 + cx;
            size_t pbase = (size_t)z * (DIM * DIM) + (size_t)y * DIM + xx;
            f32x4 a = acc[mf][nf];
            #pragma unroll
            for (int r = 0; r < 4; ++r) {
                int o = mh * 64 + mf * 16 + krow * 4 + r;
                out[(size_t)(b * COUT + o) * SP + pbase] = a[r] + bv[r];
            }
        }
    }
}

// ---------------------------------------------------------------------------
extern "C" void kernel_launch(void* const* d_in, const int* in_sizes, int n_in,
                              void* d_out, int out_size, void* d_ws, size_t ws_size,
                              hipStream_t stream) {
    const float* x       = (const float*)d_in[0];
    const float* style   = (const float*)d_in[1];
    const float* weight  = (const float*)d_in[2];
    const float* bias    = (const float*)d_in[3];
    const float* w_scale = (const float*)d_in[4];
    const float* b_scale = (const float*)d_in[5];
    const float* w_shift = (const float*)d_in[6];
    const float* b_shift = (const float*)d_in[7];
    const float* w_kmod  = (const float*)d_in[8];
    const float* b_kmod  = (const float*)d_in[9];
    float* out = (float*)d_out;
    float* ws  = (float*)d_ws;

    unsigned short* xpb  = (unsigned short*)((char*)d_ws + XPB_OFF);
    unsigned short* wsbf = (unsigned short*)((char*)d_ws + WSBF_OFF);

    {
        int waves = NB * (2 * CIN + CIN * TAPS);
        int blocks = (waves + 3) / 4;
        modparams_kernel<<<blocks, 256, 0, stream>>>(style, w_scale, b_scale,
                                                     w_shift, b_shift, w_kmod, b_kmod, ws);
    }
    {
        int n = NB * 27 * 8 * 128 * 8;
        build_wsbf2_kernel<<<(n + 255) / 256, 256, 0, stream>>>(weight, ws, wsbf);
    }
    {
        int blocks = NB * 50 * 50;
        pad_kernel<<<blocks, 256, 0, stream>>>(x, ws, xpb);
    }
    {
        int blocks = NB * 432;   // 1728
        conv_fast3_kernel<<<blocks, 512, 0, stream>>>(xpb, wsbf, bias, out);
    }
}

// Round 6
// 237.172 us; speedup vs baseline: 2.0915x; 2.0915x over previous
//
#include <hip/hip_runtime.h>
#include <hip/hip_bf16.h>

// Problem constants
#define NB   4
#define CIN  64
#define COUT 128
#define SDIM 512
#define DIM  48
#define SP   (DIM*DIM*DIM)   // 110592
#define TAPS 27
#define KTOT (CIN*TAPS)      // 1728

// ---- small-param layout (float offsets at base of ws) ----
#define WS_S1P 0                         // [NB*CIN]       1+scale
#define WS_SH  (WS_S1P + NB*CIN)         // [NB*CIN]       shift
#define WS_KM  (WS_SH + NB*CIN)          // [NB*CIN*TAPS]  kmod
// ---- fast path byte offsets ----
#define XPB_OFF   32768ull                        // padded mod x (bf16 channel-last), 64 MB
#define XPB_BYTES (4ull*125000ull*64ull*2ull)     // 64,000,000
#define WSBF_OFF  (XPB_OFF + XPB_BYTES)
#define WSBF_BYTES ((size_t)NB*27*8*128*8*2)      // 1,769,472

typedef __attribute__((ext_vector_type(4))) float  f32x4;
typedef __attribute__((ext_vector_type(8))) short  short8;
typedef __attribute__((ext_vector_type(8))) unsigned short u16x8;

__device__ __forceinline__ void gld16(const void* g, void* l) {
    __builtin_amdgcn_global_load_lds(
        (const __attribute__((address_space(1))) void*)g,
        (__attribute__((address_space(3))) void*)l, 16, 0, 0);
}

// ---------------------------------------------------------------------------
// Kernel A: style dot products. One wave per row.
// rows: [0,64)=scale, [64,128)=shift, [128,1856)=kmod, per sample b.
// ---------------------------------------------------------------------------
__global__ void modparams_kernel(const float* __restrict__ style,
                                 const float* __restrict__ w_scale, const float* __restrict__ b_scale,
                                 const float* __restrict__ w_shift, const float* __restrict__ b_shift,
                                 const float* __restrict__ w_kmod,  const float* __restrict__ b_kmod,
                                 float* __restrict__ ws) {
    const int ROWS = 2 * CIN + CIN * TAPS;  // 1856
    int gwave = (blockIdx.x * blockDim.x + threadIdx.x) >> 6;
    int lane  = threadIdx.x & 63;
    if (gwave >= NB * ROWS) return;
    int b = gwave / ROWS;
    int r = gwave % ROWS;

    const float* srow = style + b * SDIM;
    const float* mrow;
    float bias, add = 0.f;
    float* dst;
    if (r < CIN) {
        mrow = w_scale + r * SDIM; bias = b_scale[r];
        dst = ws + WS_S1P + b * CIN + r; add = 1.f;          // store (1+scale)
    } else if (r < 2 * CIN) {
        int c = r - CIN;
        mrow = w_shift + c * SDIM; bias = b_shift[c];
        dst = ws + WS_SH + b * CIN + c;
    } else {
        int t = r - 2 * CIN;
        mrow = w_kmod + t * SDIM; bias = b_kmod[t];
        dst = ws + WS_KM + b * (CIN * TAPS) + t;
    }

    float acc = 0.f;
    for (int k = lane; k < SDIM; k += 64) acc += srow[k] * mrow[k];
    #pragma unroll
    for (int off = 32; off; off >>= 1) acc += __shfl_down(acc, off);
    if (lane == 0) *dst = acc + bias + add;
}

// ---------------------------------------------------------------------------
// WSBF2[(((b*27+tau)*8 + s)*128 + o)*8 + j] = bf16(weight[o, c=s*8+j, tau] *
//                                                  (1 + kmod[b, c, tau]))
// ---------------------------------------------------------------------------
__global__ void build_wsbf2_kernel(const float* __restrict__ weight, const float* __restrict__ ws,
                                   unsigned short* __restrict__ wsbf) {
    int d = blockIdx.x * blockDim.x + threadIdx.x;
    if (d >= NB * 27 * 8 * 128 * 8) return;
    int j   = d & 7;
    int o   = (d >> 3) & 127;
    int s   = (d >> 10) & 7;
    int rem = d >> 13;
    int tau = rem % 27;
    int b   = rem / 27;
    int c   = s * 8 + j;
    float wm = weight[(o * CIN + c) * TAPS + tau] * (1.f + ws[WS_KM + b * KTOT + c * TAPS + tau]);
    __hip_bfloat16 h = __float2bfloat16(wm);
    wsbf[d] = *(unsigned short*)&h;
}

// ---------------------------------------------------------------------------
// Pad + modulate + transpose to channel-last bf16: xpb[b][pz][py][px][c]
// ---------------------------------------------------------------------------
__global__ __launch_bounds__(256) void pad_kernel(const float* __restrict__ x,
                                                  const float* __restrict__ ws,
                                                  unsigned short* __restrict__ xpb) {
    __shared__ unsigned short lxm[48 * 72];   // [w][c], row stride 144B (16B-aligned)
    int bid = blockIdx.x;
    int py = bid % 50;
    int pz = (bid / 50) % 50;
    int b  = bid / 2500;
    int t = threadIdx.x;
    bool interior = (pz >= 1 && pz <= 48 && py >= 1 && py <= 48);
    if (interior) {
        int z = pz - 1, y = py - 1;
        const float* xr = x + (size_t)b * CIN * SP + (size_t)z * (DIM*DIM) + y * DIM;
        for (int i = t; i < 3072; i += 256) {
            int c = i / 48, w = i % 48;
            float v = xr[(size_t)c * SP + w];
            float m = v * ws[WS_S1P + b * CIN + c] + ws[WS_SH + b * CIN + c];
            __hip_bfloat16 h = __float2bfloat16(m);
            lxm[w * 72 + c] = *(unsigned short*)&h;
        }
    }
    __syncthreads();
    unsigned short* dst = xpb + (size_t)b * 8000000ull + ((size_t)pz * 2500 + py * 50) * 64;
    for (int i8 = t; i8 < 400; i8 += 256) {
        int w  = i8 >> 3;          // padded px
        int c8 = (i8 & 7) * 8;
        u16x8 v = {};
        if (interior && w >= 1 && w <= 48)
            v = *(const u16x8*)&lxm[(w - 1) * 72 + c8];
        *(u16x8*)(dst + i8 * 8) = v;
    }
}

// ---------------------------------------------------------------------------
// Conv v4: block = 128 couts x 256 positions (4z x 8y x 8x box), 512 thr.
// Wave (mh, wz): 64 couts x 64 positions (z-plane wz), 4x4 fragments.
// B halo 6z x 10y x 10x x 64c bf16 in LDS (76.8 KB), staged ONCE (swizzled).
// A weights in REGISTERS, double-buffered, prefetched one tap ahead from
// global (L2-hot). ZERO barriers in the 27-tap main loop -> waves free-run.
// ---------------------------------------------------------------------------
#define HALOPOS 600   // 6*10*10

// per-tap A prefetch: 8 x global_load_dwordx4 into short8 regs
#define LOADA(dst, tap_) do {                                                  \
    _Pragma("unroll")                                                          \
    for (int j = 0; j < 8; ++j)                                                \
        dst[j] = *(const short8*)(wA + (size_t)(tap_) * 8192 +                 \
                                  (j >> 2) * 4096 + (j & 3) * 128);            \
} while (0)

#define COMPUTE(A, tap_) do {                                                  \
    int kd_ = (tap_) / 9;                                                      \
    int r9_ = (tap_) - kd_ * 9;                                                \
    int kh_ = r9_ / 3;                                                         \
    int kw_ = r9_ - kh_ * 3;                                                   \
    int pb_ = (wz + kd_) * 100 + (cy + kh_) * 10 + cx + kw_;                   \
    _Pragma("unroll")                                                          \
    for (int ch = 0; ch < 2; ++ch) {                                           \
        short8 bfr[4];                                                         \
        _Pragma("unroll")                                                      \
        for (int nf = 0; nf < 4; ++nf) {                                       \
            int pidx = pb_ + nf * 20;                                          \
            bfr[nf] = *(const short8*)&Bh[pidx * 64 +                          \
                          (((ch * 4 + krow) ^ (pidx & 7)) * 8)];               \
        }                                                                      \
        __builtin_amdgcn_s_setprio(1);                                         \
        _Pragma("unroll")                                                      \
        for (int mf = 0; mf < 4; ++mf) {                                       \
            _Pragma("unroll")                                                  \
            for (int nf = 0; nf < 4; ++nf)                                     \
                acc[mf][nf] = __builtin_amdgcn_mfma_f32_16x16x32_bf16(         \
                    A[ch * 4 + mf], bfr[nf], acc[mf][nf], 0, 0, 0);            \
        }                                                                      \
        __builtin_amdgcn_s_setprio(0);                                         \
    }                                                                          \
} while (0)

__global__ __launch_bounds__(512, 2) void conv_fast4_kernel(
    const unsigned short* __restrict__ xpb,
    const unsigned short* __restrict__ wsbf,
    const float* __restrict__ bias,
    float* __restrict__ out)
{
    __shared__ unsigned short Bh[HALOPOS * 64];   // 76,800 B

    const int t    = threadIdx.x;
    const int lane = t & 63;
    const int wid  = t >> 6;        // 0..7
    const int wz   = wid & 3;       // z-plane
    const int mh   = wid >> 2;      // M half (0/1)

    // XCD-aware bijective swizzle: 1728 = 8 * 216
    int bid0 = blockIdx.x;
    int bid  = (bid0 & 7) * 216 + (bid0 >> 3);
    int tile = bid % 432;
    int b    = bid / 432;
    int tx = tile % 6;
    int ty = (tile / 6) % 6;
    int tz = tile / 36;             // 0..11
    int x0 = tx * 8, y0 = ty * 8, z0 = tz * 4;

    const unsigned short* xb = xpb + (size_t)b * 8000000ull;
    const unsigned short* wb = wsbf + (size_t)b * (27 * 8 * 128 * 8);

    // ---- stage B halo once (source-swizzled so linear LDS == swizzled layout)
    #pragma unroll
    for (int it = 0; it < 10; ++it) {
        int i = it * 512 + t;
        if (i < HALOPOS * 8) {
            int pidx = i >> 3;
            int slot = i & 7;
            int hx = pidx % 10;
            int hy = (pidx / 10) % 10;
            int hz = pidx / 100;
            int srcslot = slot ^ (pidx & 7);
            const unsigned short* g = xb
                + ((size_t)((z0 + hz) * 2500 + (y0 + hy) * 50 + (x0 + hx))) * 64
                + srcslot * 8;
            gld16(g, &Bh[i * 8]);
        }
    }

    const int col  = lane & 15;
    const int krow = lane >> 4;   // 0..3
    const int cy   = col >> 3;    // 0..1
    const int cx   = col & 7;     // 0..7

    // per-lane A base (shorts): chunk (slot=krow.., o=mh*64+..+col)
    const unsigned short* wA = wb + (size_t)(krow * 128 + mh * 64 + col) * 8;

    f32x4 acc[4][4] = {};
    short8 a0[8], a1[8];

    LOADA(a0, 0);
    __syncthreads();   // halo staged (vmcnt drain); the ONLY block-wide barrier

    for (int tp = 0; tp < 26; tp += 2) {
        LOADA(a1, tp + 1);
        COMPUTE(a0, tp);
        LOADA(a0, tp + 2);
        COMPUTE(a1, tp + 1);
    }
    COMPUTE(a0, 26);

    // ---- epilogue: + bias, store ----
    int z = z0 + wz;
    #pragma unroll
    for (int mf = 0; mf < 4; ++mf) {
        f32x4 bv = *(const f32x4*)&bias[mh * 64 + mf * 16 + krow * 4];
        #pragma unroll
        for (int nf = 0; nf < 4; ++nf) {
            int y = y0 + nf * 2 + cy;
            int xx = x0 + cx;
            size_t pbase = (size_t)z * (DIM * DIM) + (size_t)y * DIM + xx;
            f32x4 a = acc[mf][nf];
            #pragma unroll
            for (int r = 0; r < 4; ++r) {
                int o = mh * 64 + mf * 16 + krow * 4 + r;
                out[(size_t)(b * COUT + o) * SP + pbase] = a[r] + bv[r];
            }
        }
    }
}

// ---------------------------------------------------------------------------
extern "C" void kernel_launch(void* const* d_in, const int* in_sizes, int n_in,
                              void* d_out, int out_size, void* d_ws, size_t ws_size,
                              hipStream_t stream) {
    const float* x       = (const float*)d_in[0];
    const float* style   = (const float*)d_in[1];
    const float* weight  = (const float*)d_in[2];
    const float* bias    = (const float*)d_in[3];
    const float* w_scale = (const float*)d_in[4];
    const float* b_scale = (const float*)d_in[5];
    const float* w_shift = (const float*)d_in[6];
    const float* b_shift = (const float*)d_in[7];
    const float* w_kmod  = (const float*)d_in[8];
    const float* b_kmod  = (const float*)d_in[9];
    float* out = (float*)d_out;
    float* ws  = (float*)d_ws;

    unsigned short* xpb  = (unsigned short*)((char*)d_ws + XPB_OFF);
    unsigned short* wsbf = (unsigned short*)((char*)d_ws + WSBF_OFF);

    {
        int waves = NB * (2 * CIN + CIN * TAPS);
        int blocks = (waves + 3) / 4;
        modparams_kernel<<<blocks, 256, 0, stream>>>(style, w_scale, b_scale,
                                                     w_shift, b_shift, w_kmod, b_kmod, ws);
    }
    {
        int n = NB * 27 * 8 * 128 * 8;
        build_wsbf2_kernel<<<(n + 255) / 256, 256, 0, stream>>>(weight, ws, wsbf);
    }
    {
        int blocks = NB * 50 * 50;
        pad_kernel<<<blocks, 256, 0, stream>>>(x, ws, xpb);
    }
    {
        int blocks = NB * 432;   // 1728
        conv_fast4_kernel<<<blocks, 512, 0, stream>>>(xpb, wsbf, bias, out);
    }
}